// Round 19
// baseline (89.131 us; speedup 1.0000x reference)
//
#include <hip/hip_runtime.h>
#include <hip/hip_bf16.h>
#include <math.h>

// ---------------------------------------------------------------------------
// OneClassLoss: MFMA-Gram CE + FFT2 PSD regularizer.
//   x: (200,1,256,256) fp32; masks: (600,197) i32; labels: (600,) i32
//   out: scalar fp32 = CE - 0.1 * (mean(log(avgpsd)) - log(mean(avgpsd)))
// Pipeline: rowfft (x -> T bf16, Xbt bf16-tiled) -> gc (gemm 0..47 ||
//           colfft 48..497; 256-thr blocks) -> gredu -> tail -> final.
// r19 = r18 + GNK 32->16 (Kc=4096: 48 gemm blocks x 64 steps; Pg 3.1 MB;
//       gredu reads halve again). Four slab pointers cover kc64 slabs.
// ---------------------------------------------------------------------------

#define NIMG 200
#define NROW 256
#define NCOL 256
#define NPIX 65536
#define TSTR 132          // ushort2 stride per row of row-FFT intermediate T (cols 0..128)
#define ISTR 264          // fp32 input stride in rowfft LDS
#define XSTR 273          // ushort2 transpose stride (odd -> conflict-free)
#define NCH  50           // image chunks for col-FFT partials (4 images each)
#define IPC  4            // images per chunk
#define GNK  16           // K-split chunks for Gram GEMM (Kc = 4096)
#define NST  64           // staging steps per block (BK = 64)
#define NGB  48           // gemm blocks = 3 * GNK

typedef float2 c2;
typedef short bf16x8 __attribute__((ext_vector_type(8)));
typedef unsigned short u16x8 __attribute__((ext_vector_type(8)));
typedef float f32x4  __attribute__((ext_vector_type(4)));

// LDS-ordering barrier WITHOUT vmcnt drain (r14-proven-safe).
#define BAR_LDS() do {                                            \
    __builtin_amdgcn_sched_barrier(0);                            \
    asm volatile("s_waitcnt lgkmcnt(0)" ::: "memory");            \
    __builtin_amdgcn_s_barrier();                                 \
    __builtin_amdgcn_sched_barrier(0);                            \
} while (0)

__device__ __forceinline__ unsigned short f2b(float f) {   // fp32 -> bf16 RNE
    union { float f; unsigned int u; } c; c.f = f;
    unsigned int r = (c.u + 0x7FFFu + ((c.u >> 16) & 1u)) >> 16;
    return (unsigned short)r;
}
__device__ __forceinline__ float b2f(unsigned short b) {
    union { unsigned int u; float f; } c; c.u = ((unsigned int)b) << 16;
    return c.f;
}

__device__ __forceinline__ c2 cmul(c2 a, c2 b) {
    return make_float2(a.x*b.x - a.y*b.y, a.x*b.y + a.y*b.x);
}
__device__ __forceinline__ c2 cadd(c2 a, c2 b){ return make_float2(a.x+b.x, a.y+b.y); }
__device__ __forceinline__ c2 csub(c2 a, c2 b){ return make_float2(a.x-b.x, a.y-b.y); }
__device__ __forceinline__ c2 mulmi(c2 a){ return make_float2(a.y, -a.x); }   // a * (-i)

__device__ __forceinline__ void fft4(c2& a, c2& b, c2& c, c2& d) {
    c2 t0 = cadd(a,c), t1 = csub(a,c), t2 = cadd(b,d), t3 = csub(b,d);
    a = cadd(t0,t2);
    c = csub(t0,t2);
    c2 mt3 = mulmi(t3);
    b = cadd(t1, mt3);
    d = csub(t1, mt3);
}

// 16-point DFT (radix-4 DIT, W16 twiddles as literals).
// Output X[k1+4*k2] lands in slot [4*k1+k2]  -> use R4(q) to fetch X[q].
__device__ __forceinline__ void fft16(c2 x[16]) {
    #pragma unroll
    for (int j=0;j<4;j++) fft4(x[j], x[4+j], x[8+j], x[12+j]);
    const c2 W1 = make_float2( 0.9238795325112867f,-0.3826834323650898f);
    const c2 W2 = make_float2( 0.7071067811865476f,-0.7071067811865476f);
    const c2 W3 = make_float2( 0.3826834323650898f,-0.9238795325112867f);
    const c2 W6 = make_float2(-0.7071067811865476f,-0.7071067811865476f);
    const c2 W9 = make_float2(-0.9238795325112867f, 0.3826834323650898f);
    x[5]=cmul(x[5],W1);   x[6]=cmul(x[6],W2);   x[7]=cmul(x[7],W3);
    x[9]=cmul(x[9],W2);   x[10]=mulmi(x[10]);   x[11]=cmul(x[11],W6);
    x[13]=cmul(x[13],W3); x[14]=cmul(x[14],W6); x[15]=cmul(x[15],W9);
    #pragma unroll
    for (int k1=0;k1<4;k1++) fft4(x[4*k1], x[4*k1+1], x[4*k1+2], x[4*k1+3]);
}
#define R4(q) ((((q)&3)<<2)|((q)>>2))

// ------------- fused gemm (0..47) + colfft (48..497), 256 thr --------------
// gemm: Pg[p][kcb][128][128]; p = bid/16, kcb = bid%16 (Kc=4096 = four Xbt
//   kc64 slabs). 4 waves (2Mx2N), 64x64 wave tiles: 8 ds_read_b128 -> 16
//   MFMA per ks. BK=64, 64 steps, BAR_LDS, 1-deep register prefetch.
// colfft: one 256-thread team per block (r7 body); gteam = bid-48.
__global__ __launch_bounds__(256) void k_gc(const unsigned short* __restrict__ Xb,
                                            float* __restrict__ Pg,
                                            const ushort2* __restrict__ T,
                                            float* __restrict__ Ppart) {
    __shared__ __align__(16) char smem[32768];
    int bid = blockIdx.x;
    int tid = threadIdx.x;

    if (bid < NGB) {
        // ============================ GEMM role ============================
        unsigned short* As = (unsigned short*)smem;
        unsigned short* Bs = (unsigned short*)(smem + 16384);
        int p   = bid >> 4;         // 0..2
        int kcb = bid & 15;         // 0..15
        int ti = p >> 1, tj = (p + 1) >> 1;
        bool diag = (ti == tj);
        int i0 = ti << 7, j0 = tj << 7;
        int wid = tid >> 6, lane = tid & 63;
        int wr = wid >> 1, wc = wid & 1;

        f32x4 acc[4][4];
        #pragma unroll
        for (int a=0;a<4;a++)
            #pragma unroll
            for (int b=0;b<4;b++) acc[a][b] = (f32x4){0.f,0.f,0.f,0.f};

        // staging map: thread -> row srow = tid>>1, granules gq..gq+3 (64 B)
        int srow = tid >> 1, gq = (tid & 1) * 4;
        int gia = i0 + srow; if (gia > 199) gia = 199;
        int gjb = j0 + srow; if (gjb > 199) gjb = 199;
        // Xbt[kc64][row][1024]; this block covers kc64 = 4*kcb .. 4*kcb+3
        const u16x8* Ap0 = (const u16x8*)(Xb + (((size_t)(4*kcb  )*NIMG) + gia)*1024);
        const u16x8* Ap1 = (const u16x8*)(Xb + (((size_t)(4*kcb+1)*NIMG) + gia)*1024);
        const u16x8* Ap2 = (const u16x8*)(Xb + (((size_t)(4*kcb+2)*NIMG) + gia)*1024);
        const u16x8* Ap3 = (const u16x8*)(Xb + (((size_t)(4*kcb+3)*NIMG) + gia)*1024);
        const u16x8* Bp0 = (const u16x8*)(Xb + (((size_t)(4*kcb  )*NIMG) + gjb)*1024);
        const u16x8* Bp1 = (const u16x8*)(Xb + (((size_t)(4*kcb+1)*NIMG) + gjb)*1024);
        const u16x8* Bp2 = (const u16x8*)(Xb + (((size_t)(4*kcb+2)*NIMG) + gjb)*1024);
        const u16x8* Bp3 = (const u16x8*)(Xb + (((size_t)(4*kcb+3)*NIMG) + gjb)*1024);
        int e0 = (srow*128 + (gq  )*16) ^ ((srow & 7) << 4);
        int e1 = (srow*128 + (gq+1)*16) ^ ((srow & 7) << 4);
        int e2 = (srow*128 + (gq+2)*16) ^ ((srow & 7) << 4);
        int e3 = (srow*128 + (gq+3)*16) ^ ((srow & 7) << 4);

        int swz = (lane & 7) << 3;               // fragment-read swizzle (ushorts)
        int acol0 = (lane >> 4) << 3;            // 8-elem k-slot in fragment

        u16x8 a0 = Ap0[gq], a1 = Ap0[gq+1], a2 = Ap0[gq+2], a3 = Ap0[gq+3];
        u16x8 b0, b1, b2, b3;
        if (!diag) { b0 = Bp0[gq]; b1 = Bp0[gq+1]; b2 = Bp0[gq+2]; b3 = Bp0[gq+3]; }

        #pragma unroll 1
        for (int st = 0; st < NST; ++st) {
            BAR_LDS();                           // all waves' LDS reads of st-1 done
            *(u16x8*)((char*)As + e0) = a0;
            *(u16x8*)((char*)As + e1) = a1;
            *(u16x8*)((char*)As + e2) = a2;
            *(u16x8*)((char*)As + e3) = a3;
            if (!diag) {
                *(u16x8*)((char*)Bs + e0) = b0;
                *(u16x8*)((char*)Bs + e1) = b1;
                *(u16x8*)((char*)Bs + e2) = b2;
                *(u16x8*)((char*)Bs + e3) = b3;
            }
            if (st + 1 < NST) {                  // prefetch st+1 into regs
                int ns = st + 1;
                int sl2 = ns >> 4;               // 0..3 slab index
                const u16x8* Apn = (sl2 == 0) ? Ap0 : (sl2 == 1) ? Ap1 : (sl2 == 2) ? Ap2 : Ap3;
                const u16x8* Bpn = (sl2 == 0) ? Bp0 : (sl2 == 1) ? Bp1 : (sl2 == 2) ? Bp2 : Bp3;
                int off = (ns & 15)*8 + gq;
                a0 = Apn[off]; a1 = Apn[off+1]; a2 = Apn[off+2]; a3 = Apn[off+3];
                if (!diag) { b0 = Bpn[off]; b1 = Bpn[off+1]; b2 = Bpn[off+2]; b3 = Bpn[off+3]; }
            }
            BAR_LDS();                           // LDS writes visible to all waves
            const unsigned short* Bb = diag ? As : Bs;
            #pragma unroll
            for (int ks=0; ks<2; ++ks) {
                int col = (ks*32 + acol0) ^ swz;
                bf16x8 af[4], bfv[4];
                #pragma unroll
                for (int mf=0; mf<4; ++mf) {
                    int r = wr*64 + mf*16 + (lane & 15);
                    af[mf] = *(const bf16x8*)(&As[r*64 + col]);
                }
                #pragma unroll
                for (int nf=0; nf<4; ++nf) {
                    int r = wc*64 + nf*16 + (lane & 15);
                    bfv[nf] = *(const bf16x8*)(&Bb[r*64 + col]);
                }
                #pragma unroll
                for (int mf=0; mf<4; ++mf)
                    #pragma unroll
                    for (int nf=0; nf<4; ++nf)
                        acc[mf][nf] = __builtin_amdgcn_mfma_f32_16x16x32_bf16(af[mf], bfv[nf], acc[mf][nf], 0, 0, 0);
            }
        }
        float* P = Pg + ((size_t)p*GNK + kcb)*16384;
        #pragma unroll
        for (int mf=0; mf<4; ++mf) {
            int m0 = wr*64 + mf*16 + ((lane >> 4) << 2);
            #pragma unroll
            for (int nf=0; nf<4; ++nf) {
                int n = wc*64 + nf*16 + (lane & 15);
                #pragma unroll
                for (int r2=0; r2<4; ++r2)
                    P[(size_t)(m0+r2)*128 + n] = acc[mf][nf][r2];
            }
        }
    } else {
        // ========================== COLFFT role ============================
        ushort2* sb = (ushort2*)smem;           // [16][XSTR] view
        int gteam = bid - NGB;                  // 0..449
        int cgi = gteam % 9, ic = gteam / 9;
        int c0 = cgi * 16;
        int g = tid >> 4, t = tid & 15;
        int cc = tid & 15, rb = tid >> 4;
        int cl = c0 + cc; if (cl > 128) cl = 128;
        c2 Wb;
        {
            float sv, cv;
            sincosf(-0.024543692606170259f * (float)t, &sv, &cv);
            Wb = make_float2(cv, sv);
        }
        float pacc[16];
        #pragma unroll
        for (int q=0;q<16;q++) pacc[q] = 0.f;

        for (int li=0; li<IPC; ++li) {
            int img = ic*IPC + li;
            __syncthreads();   // protect sb from previous iteration readers
            const ushort2* Tb = T + (size_t)img*NROW*TSTR;
            #pragma unroll
            for (int j=0;j<16;j++) {
                int r = rb*16 + j;
                sb[cc*XSTR + r] = Tb[(size_t)r*TSTR + cl];
            }
            __syncthreads();
            c2 y[16];
            #pragma unroll
            for (int n1=0;n1<16;n1++) {
                ushort2 u = sb[g*XSTR + 16*n1 + t];
                y[n1] = make_float2(b2f(u.x), b2f(u.y));
            }
            fft16(y);
            {
                c2 cur = Wb;
                #pragma unroll
                for (int r=1;r<16;r++) { y[R4(r)] = cmul(y[R4(r)], cur); cur = cmul(cur, Wb); }
            }
            __syncthreads();
            #pragma unroll
            for (int r=0;r<16;r++) {
                c2 v = y[R4(r)];
                sb[g*XSTR + t*17 + r] = make_ushort2(f2b(v.x), f2b(v.y));
            }
            __syncthreads();
            c2 w[16];
            #pragma unroll
            for (int n2=0;n2<16;n2++) {
                ushort2 u = sb[g*XSTR + n2*17 + t];
                w[n2] = make_float2(b2f(u.x), b2f(u.y));
            }
            fft16(w);
            #pragma unroll
            for (int q=0;q<16;q++) { c2 v = w[R4(q)]; pacc[q] += v.x*v.x + v.y*v.y; }
        }
        int c = c0 + g;
        if (c <= 128) {
            float* PP = Ppart + ((size_t)ic*132 + c)*256;
            #pragma unroll
            for (int q=0;q<16;q++) PP[q*16 + t] = pacc[q];
        }
    }
}

// --------------------------- Gram partial reduce ---------------------------
__global__ __launch_bounds__(256) void k_gredu(const float* __restrict__ Pg,
                                               float* __restrict__ dotm) {
    int idx = blockIdx.x*256 + threadIdx.x;
    if (idx >= 200*200) return;
    int i = idx / 200, j = idx - i*200;
    int ti = i >> 7, tj = j >> 7;
    int p, li, lj;
    if (ti <= tj) { p = ti + tj; li = i - (ti << 7); lj = j - (tj << 7); }
    else          { p = 1;       li = j;             lj = i - 128; }
    const float* base = Pg + (size_t)p*GNK*16384 + (size_t)li*128 + lj;
    float s0=0.f, s1=0.f, s2=0.f, s3=0.f;
    #pragma unroll 4
    for (int kc=0; kc<GNK; kc+=4) {
        s0 += base[(size_t)(kc  )*16384];
        s1 += base[(size_t)(kc+1)*16384];
        s2 += base[(size_t)(kc+2)*16384];
        s3 += base[(size_t)(kc+3)*16384];
    }
    dotm[(size_t)i*200 + j] = (s0+s1) + (s2+s3);
}

// --------------------------- row FFT pass + x->bf16 ------------------------
// 256-pt FFT per row; 16 threads per FFT; 16 rows per block. (r15-proven)
// Xb emitted in TILED layout Xbt[kc64=row>>2][img][(row&3)*256 + col].
__global__ __launch_bounds__(256) void k_rowfft(const float* __restrict__ x,
                                                ushort2* __restrict__ T,
                                                unsigned short* __restrict__ Xb) {
    __shared__ __align__(16) char ldsraw[16*XSTR*4];   // 17472 B
    float*   inpF = (float*)ldsraw;                    // [16][ISTR] fp32 view
    ushort2* tb   = (ushort2*)ldsraw;                  // [16][XSTR] bf16x2 view
    int tid = threadIdx.x;
    int img = blockIdx.y;
    int rg  = blockIdx.x;
    int g = tid >> 4, t = tid & 15;
    int row = rg*16 + g;

    // ---- Phase A: vector load row chunk, emit Xbt, stage fp32 into LDS ----
    const float4* xr = (const float4*)(x + (size_t)img*NPIX + (size_t)row*NCOL + t*16);
    float4 v0 = xr[0], v1 = xr[1], v2 = xr[2], v3 = xr[3];
    u16x8 h0, h1;
    h0[0]=f2b(v0.x); h0[1]=f2b(v0.y); h0[2]=f2b(v0.z); h0[3]=f2b(v0.w);
    h0[4]=f2b(v1.x); h0[5]=f2b(v1.y); h0[6]=f2b(v1.z); h0[7]=f2b(v1.w);
    h1[0]=f2b(v2.x); h1[1]=f2b(v2.y); h1[2]=f2b(v2.z); h1[3]=f2b(v2.w);
    h1[4]=f2b(v3.x); h1[5]=f2b(v3.y); h1[6]=f2b(v3.z); h1[7]=f2b(v3.w);
    {
        unsigned short* Xo = Xb + (((size_t)(row >> 2)*NIMG + img)*1024
                                   + (size_t)(row & 3)*256 + t*16);
        *(u16x8*)(Xo)     = h0;
        *(u16x8*)(Xo + 8) = h1;
    }
    float* ip = inpF + g*ISTR + t*16;
    *(float4*)(ip)    = v0;
    *(float4*)(ip+4)  = v1;
    *(float4*)(ip+8)  = v2;
    *(float4*)(ip+12) = v3;
    __syncthreads();

    // ---- Phase B: first fft16 over n1 (input real), twiddle chain ----
    c2 y[16];
    #pragma unroll
    for (int n1=0;n1<16;n1++) y[n1] = make_float2(inpF[g*ISTR + 16*n1 + t], 0.f);
    fft16(y);
    {
        float sv, cv;
        sincosf(-0.024543692606170259f * (float)t, &sv, &cv);  // W256^t
        c2 Wb = make_float2(cv, sv);
        c2 cur = Wb;
        #pragma unroll
        for (int r=1;r<16;r++) { y[R4(r)] = cmul(y[R4(r)], cur); cur = cmul(cur, Wb); }
    }
    __syncthreads();                       // all inpF reads done before overwrite
    #pragma unroll
    for (int r=0;r<16;r++) {
        c2 v = y[R4(r)];
        tb[g*XSTR + t*17 + r] = make_ushort2(f2b(v.x), f2b(v.y));
    }
    __syncthreads();

    // ---- Phase C: second fft16 over n2, store cols 0..128 of T ----
    c2 w[16];
    #pragma unroll
    for (int n2=0;n2<16;n2++) {
        ushort2 u = tb[g*XSTR + n2*17 + t];
        w[n2] = make_float2(b2f(u.x), b2f(u.y));
    }
    fft16(w);
    ushort2* To = T + ((size_t)img*NROW + row)*TSTR;
    #pragma unroll
    for (int q=0;q<8;q++) {
        c2 v = w[R4(q)];
        To[q*16 + t] = make_ushort2(f2b(v.x), f2b(v.y));
    }
    if (t == 0) { c2 v = w[R4(8)]; To[128] = make_ushort2(f2b(v.x), f2b(v.y)); }
}

// ----------------- tail: PSD reduce+log partials AND dist+CE ---------------
// blocks 0..128: PSD column reduce -> Pred[c].
// blocks 129..278: 4 waves, each one CE row m -> cep[m].
__global__ __launch_bounds__(256) void k_tail(const float* __restrict__ Ppart,
                                              const float* __restrict__ dotm,
                                              const int* __restrict__ masks,
                                              const int* __restrict__ labels,
                                              float* __restrict__ cep,
                                              float2* __restrict__ Pred) {
    int bid = blockIdx.x, tid = threadIdx.x;
    if (bid < 129) {
        int c = bid;
        float s = 0.f;
        for (int ic=0; ic<NCH; ++ic) s += Ppart[((size_t)ic*132 + c)*256 + tid];
        float v = s * (1.0f/200.0f);                      // avgpsd element
        float w = (c == 0 || c == 128) ? 1.f : 2.f;       // Hermitian mirror weight
        float sl = w * logf(v);
        float ss = w * v;
        __shared__ float r2[2][4];
        int wv = tid>>6, ln = tid&63;
        #pragma unroll
        for (int off=32; off>=1; off>>=1) {
            sl += __shfl_xor(sl, off);
            ss += __shfl_xor(ss, off);
        }
        if (ln == 0) { r2[0][wv] = sl; r2[1][wv] = ss; }
        __syncthreads();
        if (tid == 0)
            Pred[c] = make_float2(r2[0][0]+r2[0][1]+r2[0][2]+r2[0][3],
                                  r2[1][0]+r2[1][1]+r2[1][2]+r2[1][3]);
    } else {
        int m = (bid - 129)*4 + (tid >> 6);
        if (m >= 600) return;
        int lane = tid & 63;
        int i = m / 3;
        float sqi = dotm[(size_t)i*200 + i];
        int lbl = labels[m];
        float lg[4];
        float vmax = -1e30f, lsel = 0.f;
        #pragma unroll
        for (int k=0;k<4;k++) {
            int c = lane + 64*k;
            float v = -1e30f;
            if (c < 197) {
                int j = masks[(size_t)m*197 + c];
                float d = sqi + dotm[(size_t)j*200 + j] - 2.f*dotm[(size_t)i*200 + j];
                d = fmaxf(d, 0.f);
                v = (d == 0.f) ? 0.f : sqrtf(d);
                if (c == lbl) lsel = v;
            }
            lg[k] = v;
            vmax = fmaxf(vmax, v);
        }
        #pragma unroll
        for (int off=32; off>=1; off>>=1) vmax = fmaxf(vmax, __shfl_xor(vmax, off));
        float se = 0.f;
        #pragma unroll
        for (int k=0;k<4;k++) if (lg[k] > -1e29f) se += expf(lg[k] - vmax);
        #pragma unroll
        for (int off=32; off>=1; off>>=1) { se += __shfl_xor(se, off); lsel += __shfl_xor(lsel, off); }
        if (lane == 0) cep[m] = lsel - (vmax + logf(se));
    }
}

// --------------------------- finish ----------------------------------------
__global__ __launch_bounds__(256) void k_final(const float2* __restrict__ Pred,
                                               const float* __restrict__ cep,
                                               float* __restrict__ out) {
    int tid = threadIdx.x;
    float sl = 0.f, ss = 0.f, sce = 0.f;
    if (tid < 129) { float2 p = Pred[tid]; sl = p.x; ss = p.y; }
    for (int m = tid; m < 600; m += 256) sce += cep[m];
    __shared__ float r3[3][4];
    int wv = tid>>6, ln = tid&63;
    #pragma unroll
    for (int off=32; off>=1; off>>=1) {
        sl  += __shfl_xor(sl, off);
        ss  += __shfl_xor(ss, off);
        sce += __shfl_xor(sce, off);
    }
    if (ln == 0) { r3[0][wv]=sl; r3[1][wv]=ss; r3[2][wv]=sce; }
    __syncthreads();
    if (tid == 0) {
        float SL = r3[0][0]+r3[0][1]+r3[0][2]+r3[0][3];
        float SS = r3[1][0]+r3[1][1]+r3[1][2]+r3[1][3];
        float CE = r3[2][0]+r3[2][1]+r3[2][2]+r3[2][3];
        float ce  = -CE / 600.f;
        float psd = SL * (1.f/65536.f) - logf(SS * (1.f/65536.f));
        out[0] = ce - 0.1f * psd;
    }
}

// ---------------------------------------------------------------------------
extern "C" void kernel_launch(void* const* d_in, const int* in_sizes, int n_in,
                              void* d_out, int out_size, void* d_ws, size_t ws_size,
                              hipStream_t stream) {
    const float* x      = (const float*)d_in[0];
    const int*   masks  = (const int*)d_in[1];
    const int*   labels = (const int*)d_in[2];
    float* out = (float*)d_out;
    char* ws = (char*)d_ws;

    const size_t OFF_DOT = 0;             // 200*200*4      = 160000
    const size_t OFF_CE  = 160256;        // 600*4
    const size_t OFF_PR  = 162688;        // 129*8
    const size_t OFF_PP  = 163840;        // 50*132*256*4   = 6758400   -> ends  6922240
    const size_t OFF_T   = 6922240;       // 200*256*132*4  = 27033600  -> ends 33955840
    const size_t OFF_XB  = 33955840;      // 64*200*1024*2  = 26214400  -> ends 60170240
    const size_t OFF_PG  = 60170240;      // 3*16*128*128*4 = 3145728   -> ends 63315968
    const size_t NEED    = 63315968;      // ~63.3 MB
    if (ws_size < NEED) return;           // fails loudly (out stays zero)

    float*          dotm = (float*)(ws + OFF_DOT);
    float*          cep  = (float*)(ws + OFF_CE);
    float2*         Pr   = (float2*)(ws + OFF_PR);
    float*          Pp   = (float*)(ws + OFF_PP);
    ushort2*        T    = (ushort2*)(ws + OFF_T);
    unsigned short* Xb   = (unsigned short*)(ws + OFF_XB);
    float*          Pg   = (float*)(ws + OFF_PG);

    k_rowfft<<<dim3(16,200), dim3(256), 0, stream>>>(x, T, Xb);
    k_gc    <<<dim3(498),    dim3(256), 0, stream>>>(Xb, Pg, T, Pp);
    k_gredu <<<dim3(157),    dim3(256), 0, stream>>>(Pg, dotm);
    k_tail  <<<dim3(279),    dim3(256), 0, stream>>>(Pp, dotm, masks, labels, cep, Pr);
    k_final <<<dim3(1),      dim3(256), 0, stream>>>(Pr, cep, out);
}

// Round 20
// 67.933 us; speedup vs baseline: 1.3120x; 1.3120x over previous
//
#include <hip/hip_runtime.h>
#include <hip/hip_bf16.h>
#include <math.h>

// ---------------------------------------------------------------------------
// OneClassLoss: MFMA-Gram CE + FFT2 PSD regularizer.
//   x: (200,1,256,256) fp32; masks: (600,197) i32; labels: (600,) i32
//   out: scalar fp32 = CE - 0.1 * (mean(log(avgpsd)) - log(mean(avgpsd)))
// Pipeline: rowfft (x -> T bf16, Xbt bf16-tiled) -> gc (gemm 0..95 ||
//           colfft 96..545; 256-thr blocks) -> gredu -> tail -> final.
// r20 = r18 verbatim (proven best, 68.2 us). GNK=32 is the verified optimum:
//   GNK 64->32 = -4 us (Pg traffic), 32->16 = +21 us (gemm chain too long).
// ---------------------------------------------------------------------------

#define NIMG 200
#define NROW 256
#define NCOL 256
#define NPIX 65536
#define TSTR 132          // ushort2 stride per row of row-FFT intermediate T (cols 0..128)
#define ISTR 264          // fp32 input stride in rowfft LDS
#define XSTR 273          // ushort2 transpose stride (odd -> conflict-free)
#define NCH  50           // image chunks for col-FFT partials (4 images each)
#define IPC  4            // images per chunk
#define GNK  32           // K-split chunks for Gram GEMM (Kc = 2048)
#define NST  32           // staging steps per block (BK = 64)
#define NGB  96           // gemm blocks = 3 * GNK

typedef float2 c2;
typedef short bf16x8 __attribute__((ext_vector_type(8)));
typedef unsigned short u16x8 __attribute__((ext_vector_type(8)));
typedef float f32x4  __attribute__((ext_vector_type(4)));

// LDS-ordering barrier WITHOUT vmcnt drain (r14-proven-safe).
#define BAR_LDS() do {                                            \
    __builtin_amdgcn_sched_barrier(0);                            \
    asm volatile("s_waitcnt lgkmcnt(0)" ::: "memory");            \
    __builtin_amdgcn_s_barrier();                                 \
    __builtin_amdgcn_sched_barrier(0);                            \
} while (0)

__device__ __forceinline__ unsigned short f2b(float f) {   // fp32 -> bf16 RNE
    union { float f; unsigned int u; } c; c.f = f;
    unsigned int r = (c.u + 0x7FFFu + ((c.u >> 16) & 1u)) >> 16;
    return (unsigned short)r;
}
__device__ __forceinline__ float b2f(unsigned short b) {
    union { unsigned int u; float f; } c; c.u = ((unsigned int)b) << 16;
    return c.f;
}

__device__ __forceinline__ c2 cmul(c2 a, c2 b) {
    return make_float2(a.x*b.x - a.y*b.y, a.x*b.y + a.y*b.x);
}
__device__ __forceinline__ c2 cadd(c2 a, c2 b){ return make_float2(a.x+b.x, a.y+b.y); }
__device__ __forceinline__ c2 csub(c2 a, c2 b){ return make_float2(a.x-b.x, a.y-b.y); }
__device__ __forceinline__ c2 mulmi(c2 a){ return make_float2(a.y, -a.x); }   // a * (-i)

__device__ __forceinline__ void fft4(c2& a, c2& b, c2& c, c2& d) {
    c2 t0 = cadd(a,c), t1 = csub(a,c), t2 = cadd(b,d), t3 = csub(b,d);
    a = cadd(t0,t2);
    c = csub(t0,t2);
    c2 mt3 = mulmi(t3);
    b = cadd(t1, mt3);
    d = csub(t1, mt3);
}

// 16-point DFT (radix-4 DIT, W16 twiddles as literals).
// Output X[k1+4*k2] lands in slot [4*k1+k2]  -> use R4(q) to fetch X[q].
__device__ __forceinline__ void fft16(c2 x[16]) {
    #pragma unroll
    for (int j=0;j<4;j++) fft4(x[j], x[4+j], x[8+j], x[12+j]);
    const c2 W1 = make_float2( 0.9238795325112867f,-0.3826834323650898f);
    const c2 W2 = make_float2( 0.7071067811865476f,-0.7071067811865476f);
    const c2 W3 = make_float2( 0.3826834323650898f,-0.9238795325112867f);
    const c2 W6 = make_float2(-0.7071067811865476f,-0.7071067811865476f);
    const c2 W9 = make_float2(-0.9238795325112867f, 0.3826834323650898f);
    x[5]=cmul(x[5],W1);   x[6]=cmul(x[6],W2);   x[7]=cmul(x[7],W3);
    x[9]=cmul(x[9],W2);   x[10]=mulmi(x[10]);   x[11]=cmul(x[11],W6);
    x[13]=cmul(x[13],W3); x[14]=cmul(x[14],W6); x[15]=cmul(x[15],W9);
    #pragma unroll
    for (int k1=0;k1<4;k1++) fft4(x[4*k1], x[4*k1+1], x[4*k1+2], x[4*k1+3]);
}
#define R4(q) ((((q)&3)<<2)|((q)>>2))

// ------------- fused gemm (0..95) + colfft (96..545), 256 thr --------------
// gemm: Pg[p][kcb][128][128]; p = bid/32, kcb = bid%32 (Kc=2048 = two Xbt
//   kc64 slabs). 4 waves (2Mx2N), 64x64 wave tiles: 8 ds_read_b128 -> 16
//   MFMA per ks. BK=64, 32 steps, BAR_LDS, 1-deep register prefetch.
// colfft: one 256-thread team per block (r7 body); gteam = bid-96.
__global__ __launch_bounds__(256) void k_gc(const unsigned short* __restrict__ Xb,
                                            float* __restrict__ Pg,
                                            const ushort2* __restrict__ T,
                                            float* __restrict__ Ppart) {
    __shared__ __align__(16) char smem[32768];
    int bid = blockIdx.x;
    int tid = threadIdx.x;

    if (bid < NGB) {
        // ============================ GEMM role ============================
        unsigned short* As = (unsigned short*)smem;
        unsigned short* Bs = (unsigned short*)(smem + 16384);
        int p   = bid >> 5;         // 0..2
        int kcb = bid & 31;         // 0..31
        int ti = p >> 1, tj = (p + 1) >> 1;
        bool diag = (ti == tj);
        int i0 = ti << 7, j0 = tj << 7;
        int wid = tid >> 6, lane = tid & 63;
        int wr = wid >> 1, wc = wid & 1;

        f32x4 acc[4][4];
        #pragma unroll
        for (int a=0;a<4;a++)
            #pragma unroll
            for (int b=0;b<4;b++) acc[a][b] = (f32x4){0.f,0.f,0.f,0.f};

        // staging map: thread -> row srow = tid>>1, granules gq..gq+3 (64 B)
        int srow = tid >> 1, gq = (tid & 1) * 4;
        int gia = i0 + srow; if (gia > 199) gia = 199;
        int gjb = j0 + srow; if (gjb > 199) gjb = 199;
        // Xbt[kc64][row][1024]; this block covers kc64 = 2*kcb and 2*kcb+1
        const u16x8* Ap0 = (const u16x8*)(Xb + (((size_t)(2*kcb  )*NIMG) + gia)*1024);
        const u16x8* Ap1 = (const u16x8*)(Xb + (((size_t)(2*kcb+1)*NIMG) + gia)*1024);
        const u16x8* Bp0 = (const u16x8*)(Xb + (((size_t)(2*kcb  )*NIMG) + gjb)*1024);
        const u16x8* Bp1 = (const u16x8*)(Xb + (((size_t)(2*kcb+1)*NIMG) + gjb)*1024);
        int e0 = (srow*128 + (gq  )*16) ^ ((srow & 7) << 4);
        int e1 = (srow*128 + (gq+1)*16) ^ ((srow & 7) << 4);
        int e2 = (srow*128 + (gq+2)*16) ^ ((srow & 7) << 4);
        int e3 = (srow*128 + (gq+3)*16) ^ ((srow & 7) << 4);

        int swz = (lane & 7) << 3;               // fragment-read swizzle (ushorts)
        int acol0 = (lane >> 4) << 3;            // 8-elem k-slot in fragment

        u16x8 a0 = Ap0[gq], a1 = Ap0[gq+1], a2 = Ap0[gq+2], a3 = Ap0[gq+3];
        u16x8 b0, b1, b2, b3;
        if (!diag) { b0 = Bp0[gq]; b1 = Bp0[gq+1]; b2 = Bp0[gq+2]; b3 = Bp0[gq+3]; }

        #pragma unroll 1
        for (int st = 0; st < NST; ++st) {
            BAR_LDS();                           // all waves' LDS reads of st-1 done
            *(u16x8*)((char*)As + e0) = a0;
            *(u16x8*)((char*)As + e1) = a1;
            *(u16x8*)((char*)As + e2) = a2;
            *(u16x8*)((char*)As + e3) = a3;
            if (!diag) {
                *(u16x8*)((char*)Bs + e0) = b0;
                *(u16x8*)((char*)Bs + e1) = b1;
                *(u16x8*)((char*)Bs + e2) = b2;
                *(u16x8*)((char*)Bs + e3) = b3;
            }
            if (st + 1 < NST) {                  // prefetch st+1 into regs
                int ns = st + 1;
                const u16x8* Apn = (ns < 16) ? Ap0 : Ap1;
                const u16x8* Bpn = (ns < 16) ? Bp0 : Bp1;
                int off = (ns & 15)*8 + gq;
                a0 = Apn[off]; a1 = Apn[off+1]; a2 = Apn[off+2]; a3 = Apn[off+3];
                if (!diag) { b0 = Bpn[off]; b1 = Bpn[off+1]; b2 = Bpn[off+2]; b3 = Bpn[off+3]; }
            }
            BAR_LDS();                           // LDS writes visible to all waves
            const unsigned short* Bb = diag ? As : Bs;
            #pragma unroll
            for (int ks=0; ks<2; ++ks) {
                int col = (ks*32 + acol0) ^ swz;
                bf16x8 af[4], bfv[4];
                #pragma unroll
                for (int mf=0; mf<4; ++mf) {
                    int r = wr*64 + mf*16 + (lane & 15);
                    af[mf] = *(const bf16x8*)(&As[r*64 + col]);
                }
                #pragma unroll
                for (int nf=0; nf<4; ++nf) {
                    int r = wc*64 + nf*16 + (lane & 15);
                    bfv[nf] = *(const bf16x8*)(&Bb[r*64 + col]);
                }
                #pragma unroll
                for (int mf=0; mf<4; ++mf)
                    #pragma unroll
                    for (int nf=0; nf<4; ++nf)
                        acc[mf][nf] = __builtin_amdgcn_mfma_f32_16x16x32_bf16(af[mf], bfv[nf], acc[mf][nf], 0, 0, 0);
            }
        }
        float* P = Pg + ((size_t)p*GNK + kcb)*16384;
        #pragma unroll
        for (int mf=0; mf<4; ++mf) {
            int m0 = wr*64 + mf*16 + ((lane >> 4) << 2);
            #pragma unroll
            for (int nf=0; nf<4; ++nf) {
                int n = wc*64 + nf*16 + (lane & 15);
                #pragma unroll
                for (int r2=0; r2<4; ++r2)
                    P[(size_t)(m0+r2)*128 + n] = acc[mf][nf][r2];
            }
        }
    } else {
        // ========================== COLFFT role ============================
        ushort2* sb = (ushort2*)smem;           // [16][XSTR] view
        int gteam = bid - NGB;                  // 0..449
        int cgi = gteam % 9, ic = gteam / 9;
        int c0 = cgi * 16;
        int g = tid >> 4, t = tid & 15;
        int cc = tid & 15, rb = tid >> 4;
        int cl = c0 + cc; if (cl > 128) cl = 128;
        c2 Wb;
        {
            float sv, cv;
            sincosf(-0.024543692606170259f * (float)t, &sv, &cv);
            Wb = make_float2(cv, sv);
        }
        float pacc[16];
        #pragma unroll
        for (int q=0;q<16;q++) pacc[q] = 0.f;

        for (int li=0; li<IPC; ++li) {
            int img = ic*IPC + li;
            __syncthreads();   // protect sb from previous iteration readers
            const ushort2* Tb = T + (size_t)img*NROW*TSTR;
            #pragma unroll
            for (int j=0;j<16;j++) {
                int r = rb*16 + j;
                sb[cc*XSTR + r] = Tb[(size_t)r*TSTR + cl];
            }
            __syncthreads();
            c2 y[16];
            #pragma unroll
            for (int n1=0;n1<16;n1++) {
                ushort2 u = sb[g*XSTR + 16*n1 + t];
                y[n1] = make_float2(b2f(u.x), b2f(u.y));
            }
            fft16(y);
            {
                c2 cur = Wb;
                #pragma unroll
                for (int r=1;r<16;r++) { y[R4(r)] = cmul(y[R4(r)], cur); cur = cmul(cur, Wb); }
            }
            __syncthreads();
            #pragma unroll
            for (int r=0;r<16;r++) {
                c2 v = y[R4(r)];
                sb[g*XSTR + t*17 + r] = make_ushort2(f2b(v.x), f2b(v.y));
            }
            __syncthreads();
            c2 w[16];
            #pragma unroll
            for (int n2=0;n2<16;n2++) {
                ushort2 u = sb[g*XSTR + n2*17 + t];
                w[n2] = make_float2(b2f(u.x), b2f(u.y));
            }
            fft16(w);
            #pragma unroll
            for (int q=0;q<16;q++) { c2 v = w[R4(q)]; pacc[q] += v.x*v.x + v.y*v.y; }
        }
        int c = c0 + g;
        if (c <= 128) {
            float* PP = Ppart + ((size_t)ic*132 + c)*256;
            #pragma unroll
            for (int q=0;q<16;q++) PP[q*16 + t] = pacc[q];
        }
    }
}

// --------------------------- Gram partial reduce ---------------------------
__global__ __launch_bounds__(256) void k_gredu(const float* __restrict__ Pg,
                                               float* __restrict__ dotm) {
    int idx = blockIdx.x*256 + threadIdx.x;
    if (idx >= 200*200) return;
    int i = idx / 200, j = idx - i*200;
    int ti = i >> 7, tj = j >> 7;
    int p, li, lj;
    if (ti <= tj) { p = ti + tj; li = i - (ti << 7); lj = j - (tj << 7); }
    else          { p = 1;       li = j;             lj = i - 128; }
    const float* base = Pg + (size_t)p*GNK*16384 + (size_t)li*128 + lj;
    float s0=0.f, s1=0.f, s2=0.f, s3=0.f;
    #pragma unroll 4
    for (int kc=0; kc<GNK; kc+=4) {
        s0 += base[(size_t)(kc  )*16384];
        s1 += base[(size_t)(kc+1)*16384];
        s2 += base[(size_t)(kc+2)*16384];
        s3 += base[(size_t)(kc+3)*16384];
    }
    dotm[(size_t)i*200 + j] = (s0+s1) + (s2+s3);
}

// --------------------------- row FFT pass + x->bf16 ------------------------
// 256-pt FFT per row; 16 threads per FFT; 16 rows per block. (r15-proven)
// Xb emitted in TILED layout Xbt[kc64=row>>2][img][(row&3)*256 + col].
__global__ __launch_bounds__(256) void k_rowfft(const float* __restrict__ x,
                                                ushort2* __restrict__ T,
                                                unsigned short* __restrict__ Xb) {
    __shared__ __align__(16) char ldsraw[16*XSTR*4];   // 17472 B
    float*   inpF = (float*)ldsraw;                    // [16][ISTR] fp32 view
    ushort2* tb   = (ushort2*)ldsraw;                  // [16][XSTR] bf16x2 view
    int tid = threadIdx.x;
    int img = blockIdx.y;
    int rg  = blockIdx.x;
    int g = tid >> 4, t = tid & 15;
    int row = rg*16 + g;

    // ---- Phase A: vector load row chunk, emit Xbt, stage fp32 into LDS ----
    const float4* xr = (const float4*)(x + (size_t)img*NPIX + (size_t)row*NCOL + t*16);
    float4 v0 = xr[0], v1 = xr[1], v2 = xr[2], v3 = xr[3];
    u16x8 h0, h1;
    h0[0]=f2b(v0.x); h0[1]=f2b(v0.y); h0[2]=f2b(v0.z); h0[3]=f2b(v0.w);
    h0[4]=f2b(v1.x); h0[5]=f2b(v1.y); h0[6]=f2b(v1.z); h0[7]=f2b(v1.w);
    h1[0]=f2b(v2.x); h1[1]=f2b(v2.y); h1[2]=f2b(v2.z); h1[3]=f2b(v2.w);
    h1[4]=f2b(v3.x); h1[5]=f2b(v3.y); h1[6]=f2b(v3.z); h1[7]=f2b(v3.w);
    {
        unsigned short* Xo = Xb + (((size_t)(row >> 2)*NIMG + img)*1024
                                   + (size_t)(row & 3)*256 + t*16);
        *(u16x8*)(Xo)     = h0;
        *(u16x8*)(Xo + 8) = h1;
    }
    float* ip = inpF + g*ISTR + t*16;
    *(float4*)(ip)    = v0;
    *(float4*)(ip+4)  = v1;
    *(float4*)(ip+8)  = v2;
    *(float4*)(ip+12) = v3;
    __syncthreads();

    // ---- Phase B: first fft16 over n1 (input real), twiddle chain ----
    c2 y[16];
    #pragma unroll
    for (int n1=0;n1<16;n1++) y[n1] = make_float2(inpF[g*ISTR + 16*n1 + t], 0.f);
    fft16(y);
    {
        float sv, cv;
        sincosf(-0.024543692606170259f * (float)t, &sv, &cv);  // W256^t
        c2 Wb = make_float2(cv, sv);
        c2 cur = Wb;
        #pragma unroll
        for (int r=1;r<16;r++) { y[R4(r)] = cmul(y[R4(r)], cur); cur = cmul(cur, Wb); }
    }
    __syncthreads();                       // all inpF reads done before overwrite
    #pragma unroll
    for (int r=0;r<16;r++) {
        c2 v = y[R4(r)];
        tb[g*XSTR + t*17 + r] = make_ushort2(f2b(v.x), f2b(v.y));
    }
    __syncthreads();

    // ---- Phase C: second fft16 over n2, store cols 0..128 of T ----
    c2 w[16];
    #pragma unroll
    for (int n2=0;n2<16;n2++) {
        ushort2 u = tb[g*XSTR + n2*17 + t];
        w[n2] = make_float2(b2f(u.x), b2f(u.y));
    }
    fft16(w);
    ushort2* To = T + ((size_t)img*NROW + row)*TSTR;
    #pragma unroll
    for (int q=0;q<8;q++) {
        c2 v = w[R4(q)];
        To[q*16 + t] = make_ushort2(f2b(v.x), f2b(v.y));
    }
    if (t == 0) { c2 v = w[R4(8)]; To[128] = make_ushort2(f2b(v.x), f2b(v.y)); }
}

// ----------------- tail: PSD reduce+log partials AND dist+CE ---------------
// blocks 0..128: PSD column reduce -> Pred[c].
// blocks 129..278: 4 waves, each one CE row m -> cep[m].
__global__ __launch_bounds__(256) void k_tail(const float* __restrict__ Ppart,
                                              const float* __restrict__ dotm,
                                              const int* __restrict__ masks,
                                              const int* __restrict__ labels,
                                              float* __restrict__ cep,
                                              float2* __restrict__ Pred) {
    int bid = blockIdx.x, tid = threadIdx.x;
    if (bid < 129) {
        int c = bid;
        float s = 0.f;
        for (int ic=0; ic<NCH; ++ic) s += Ppart[((size_t)ic*132 + c)*256 + tid];
        float v = s * (1.0f/200.0f);                      // avgpsd element
        float w = (c == 0 || c == 128) ? 1.f : 2.f;       // Hermitian mirror weight
        float sl = w * logf(v);
        float ss = w * v;
        __shared__ float r2[2][4];
        int wv = tid>>6, ln = tid&63;
        #pragma unroll
        for (int off=32; off>=1; off>>=1) {
            sl += __shfl_xor(sl, off);
            ss += __shfl_xor(ss, off);
        }
        if (ln == 0) { r2[0][wv] = sl; r2[1][wv] = ss; }
        __syncthreads();
        if (tid == 0)
            Pred[c] = make_float2(r2[0][0]+r2[0][1]+r2[0][2]+r2[0][3],
                                  r2[1][0]+r2[1][1]+r2[1][2]+r2[1][3]);
    } else {
        int m = (bid - 129)*4 + (tid >> 6);
        if (m >= 600) return;
        int lane = tid & 63;
        int i = m / 3;
        float sqi = dotm[(size_t)i*200 + i];
        int lbl = labels[m];
        float lg[4];
        float vmax = -1e30f, lsel = 0.f;
        #pragma unroll
        for (int k=0;k<4;k++) {
            int c = lane + 64*k;
            float v = -1e30f;
            if (c < 197) {
                int j = masks[(size_t)m*197 + c];
                float d = sqi + dotm[(size_t)j*200 + j] - 2.f*dotm[(size_t)i*200 + j];
                d = fmaxf(d, 0.f);
                v = (d == 0.f) ? 0.f : sqrtf(d);
                if (c == lbl) lsel = v;
            }
            lg[k] = v;
            vmax = fmaxf(vmax, v);
        }
        #pragma unroll
        for (int off=32; off>=1; off>>=1) vmax = fmaxf(vmax, __shfl_xor(vmax, off));
        float se = 0.f;
        #pragma unroll
        for (int k=0;k<4;k++) if (lg[k] > -1e29f) se += expf(lg[k] - vmax);
        #pragma unroll
        for (int off=32; off>=1; off>>=1) { se += __shfl_xor(se, off); lsel += __shfl_xor(lsel, off); }
        if (lane == 0) cep[m] = lsel - (vmax + logf(se));
    }
}

// --------------------------- finish ----------------------------------------
__global__ __launch_bounds__(256) void k_final(const float2* __restrict__ Pred,
                                               const float* __restrict__ cep,
                                               float* __restrict__ out) {
    int tid = threadIdx.x;
    float sl = 0.f, ss = 0.f, sce = 0.f;
    if (tid < 129) { float2 p = Pred[tid]; sl = p.x; ss = p.y; }
    for (int m = tid; m < 600; m += 256) sce += cep[m];
    __shared__ float r3[3][4];
    int wv = tid>>6, ln = tid&63;
    #pragma unroll
    for (int off=32; off>=1; off>>=1) {
        sl  += __shfl_xor(sl, off);
        ss  += __shfl_xor(ss, off);
        sce += __shfl_xor(sce, off);
    }
    if (ln == 0) { r3[0][wv]=sl; r3[1][wv]=ss; r3[2][wv]=sce; }
    __syncthreads();
    if (tid == 0) {
        float SL = r3[0][0]+r3[0][1]+r3[0][2]+r3[0][3];
        float SS = r3[1][0]+r3[1][1]+r3[1][2]+r3[1][3];
        float CE = r3[2][0]+r3[2][1]+r3[2][2]+r3[2][3];
        float ce  = -CE / 600.f;
        float psd = SL * (1.f/65536.f) - logf(SS * (1.f/65536.f));
        out[0] = ce - 0.1f * psd;
    }
}

// ---------------------------------------------------------------------------
extern "C" void kernel_launch(void* const* d_in, const int* in_sizes, int n_in,
                              void* d_out, int out_size, void* d_ws, size_t ws_size,
                              hipStream_t stream) {
    const float* x      = (const float*)d_in[0];
    const int*   masks  = (const int*)d_in[1];
    const int*   labels = (const int*)d_in[2];
    float* out = (float*)d_out;
    char* ws = (char*)d_ws;

    const size_t OFF_DOT = 0;             // 200*200*4      = 160000
    const size_t OFF_CE  = 160256;        // 600*4
    const size_t OFF_PR  = 162688;        // 129*8
    const size_t OFF_PP  = 163840;        // 50*132*256*4   = 6758400   -> ends  6922240
    const size_t OFF_T   = 6922240;       // 200*256*132*4  = 27033600  -> ends 33955840
    const size_t OFF_XB  = 33955840;      // 64*200*1024*2  = 26214400  -> ends 60170240
    const size_t OFF_PG  = 60170240;      // 3*32*128*128*4 = 6291456   -> ends 66461696
    const size_t NEED    = 66461696;      // ~66.5 MB
    if (ws_size < NEED) return;           // fails loudly (out stays zero)

    float*          dotm = (float*)(ws + OFF_DOT);
    float*          cep  = (float*)(ws + OFF_CE);
    float2*         Pr   = (float2*)(ws + OFF_PR);
    float*          Pp   = (float*)(ws + OFF_PP);
    ushort2*        T    = (ushort2*)(ws + OFF_T);
    unsigned short* Xb   = (unsigned short*)(ws + OFF_XB);
    float*          Pg   = (float*)(ws + OFF_PG);

    k_rowfft<<<dim3(16,200), dim3(256), 0, stream>>>(x, T, Xb);
    k_gc    <<<dim3(546),    dim3(256), 0, stream>>>(Xb, Pg, T, Pp);
    k_gredu <<<dim3(157),    dim3(256), 0, stream>>>(Pg, dotm);
    k_tail  <<<dim3(279),    dim3(256), 0, stream>>>(Pp, dotm, masks, labels, cep, Pr);
    k_final <<<dim3(1),      dim3(256), 0, stream>>>(Pr, cep, out);
}